// Round 1
// baseline (242.500 us; speedup 1.0000x reference)
//
#include <hip/hip_runtime.h>
#include <hip/hip_bf16.h>
#include <stdint.h>

// out[b,o,k] = sum_{h,m} W[o, h*64+m] * xl[b,h,k] * x0[b,m,k] + bias[o]
// B=256, M=H=64, K=128, OUT=256, C=H*M=4096.
// Per-b GEMM: out[b] = W[256x4096] @ fmap_b[4096x128], fmap generated on the
// fly in registers as the MFMA B-fragment from LDS-staged bf16 xl / x0^T.

typedef __attribute__((ext_vector_type(8))) short short8;
typedef __attribute__((ext_vector_type(4))) float f32x4;

#define B_SZ   256
#define M_SZ   64
#define H_SZ   64
#define K_SZ   128
#define OUT_SZ 256
#define C_SZ   4096

#define X0T_STRIDE 72   // pad 64->72 elems: keeps 16B alignment, spreads banks

__device__ __forceinline__ float bf2f(short s) {
    union { uint32_t u; float f; } v;
    v.u = ((uint32_t)(uint16_t)s) << 16;
    return v.f;
}

__device__ __forceinline__ short f2bfs(float f) {
    __hip_bfloat16 h = __float2bfloat16(f);
    union { __hip_bfloat16 h; short s; } v;
    v.h = h;
    return v.s;
}

__device__ __forceinline__ uint32_t pack_bf16(float a, float b) {
    __hip_bfloat162 h2 = __float22bfloat162_rn(make_float2(a, b));
    union { __hip_bfloat162 h; uint32_t u; } v;
    v.h = h2;
    return v.u;
}

// ---- W f32 -> bf16 conversion (runs once per launch; W is 1M elems) ----
__global__ void convert_W(const float* __restrict__ W, short* __restrict__ Wb, int n) {
    int i = (blockIdx.x * blockDim.x + threadIdx.x) * 4;
    if (i + 3 >= n) {
        if (i >= n) return;
        for (int j = 0; j < 4 && i + j < n; ++j) Wb[i + j] = f2bfs(W[i + j]);
        return;
    }
    float4 v = *(const float4*)(W + i);
    union { uint32_t u[2]; } o;
    o.u[0] = pack_bf16(v.x, v.y);
    o.u[1] = pack_bf16(v.z, v.w);
    *(uint2*)(Wb + i) = *(uint2*)&o;
}

// ---- main kernel ----
// grid (2, 256): blockIdx.x = o-half (128 rows), blockIdx.y = b
// 512 threads = 8 waves: wave_o = wave>>2 (2), wave_k = wave&3 (4)
// wave tile: 64 (o) x 32 (k); frags: 4 o-tiles x 2 n-tiles of 16x16
template<bool USE_WS>
__global__ __launch_bounds__(512)
void cin_main(const float* __restrict__ x0, const float* __restrict__ xl,
              const float* __restrict__ Wf, const short* __restrict__ Wb,
              const float* __restrict__ bias, float* __restrict__ out) {
    __shared__ short x0T[K_SZ * X0T_STRIDE];   // [k=128][m=64 (+pad)] bf16
    __shared__ short xls[H_SZ * K_SZ];         // [h=64][k=128] bf16

    const int b     = blockIdx.y;
    const int ohalf = blockIdx.x;               // 0..1
    const int tid   = threadIdx.x;
    const int lane  = tid & 63;
    const int wave  = tid >> 6;                 // 0..7
    const int wave_k = wave & 3;                // k offset *32
    const int wave_o = wave >> 2;               // o offset *64
    const int row_lane = lane & 15;
    const int kgrp  = lane >> 4;                // 0..3

    // ---------- stage x0^T (bf16) and xl (bf16) into LDS ----------
    {
        const float* x0b = x0 + (size_t)b * (M_SZ * K_SZ);
        const float* xlb = xl + (size_t)b * (H_SZ * K_SZ);
        const int idx0 = tid * 16;
        const int m  = idx0 >> 7;     // 0..63
        const int k0 = idx0 & 127;    // multiple of 16

        float vals[16];
        *(float4*)(vals + 0)  = *(const float4*)(x0b + m * K_SZ + k0 + 0);
        *(float4*)(vals + 4)  = *(const float4*)(x0b + m * K_SZ + k0 + 4);
        *(float4*)(vals + 8)  = *(const float4*)(x0b + m * K_SZ + k0 + 8);
        *(float4*)(vals + 12) = *(const float4*)(x0b + m * K_SZ + k0 + 12);
#pragma unroll
        for (int j = 0; j < 16; ++j)
            x0T[(k0 + j) * X0T_STRIDE + m] = f2bfs(vals[j]);

        *(float4*)(vals + 0)  = *(const float4*)(xlb + m * K_SZ + k0 + 0);
        *(float4*)(vals + 4)  = *(const float4*)(xlb + m * K_SZ + k0 + 4);
        *(float4*)(vals + 8)  = *(const float4*)(xlb + m * K_SZ + k0 + 8);
        *(float4*)(vals + 12) = *(const float4*)(xlb + m * K_SZ + k0 + 12);
        uint32_t* xlp = (uint32_t*)&xls[m * K_SZ + k0];
#pragma unroll
        for (int jj = 0; jj < 8; ++jj)
            xlp[jj] = pack_bf16(vals[2 * jj], vals[2 * jj + 1]);
    }
    __syncthreads();

    const int obase = ohalf * 128 + wave_o * 64;
    const int nbase = wave_k * 32 + row_lane;     // n for nt=0 (+16 for nt=1)

    f32x4 acc[4][2];
#pragma unroll
    for (int ot = 0; ot < 4; ++ot)
#pragma unroll
        for (int nt = 0; nt < 2; ++nt)
            acc[ot][nt] = (f32x4){0.f, 0.f, 0.f, 0.f};

    // per-thread operand base pointers
    const short* wrow[4];
    const float* wrowf[4];
#pragma unroll
    for (int ot = 0; ot < 4; ++ot) {
        const int o_row = obase + ot * 16 + row_lane;
        if (USE_WS) wrow[ot]  = Wb + (size_t)o_row * C_SZ + kgrp * 8;
        else        wrowf[ot] = Wf + (size_t)o_row * C_SZ + kgrp * 8;
    }
    const short* x0Tp0 = x0T + nbase * X0T_STRIDE + kgrp * 8;
    const short* x0Tp1 = x0T + (nbase + 16) * X0T_STRIDE + kgrp * 8;
    const short* xlsp  = xls + wave_k * 32 + row_lane;

    for (int h = 0; h < H_SZ; ++h) {
        const float xlv0 = bf2f(xlsp[h * K_SZ]);
        const float xlv1 = bf2f(xlsp[h * K_SZ + 16]);
#pragma unroll
        for (int m0 = 0; m0 < 64; m0 += 32) {
            const int cbase = h * 64 + m0;

            // B fragments: fmap[c = cbase + kgrp*8 + j, n] = xl[h,n] * x0[m,n]
            const short8 xa = *(const short8*)(x0Tp0 + m0);
            const short8 xb = *(const short8*)(x0Tp1 + m0);
            union { short8 s; uint32_t u[4]; } bf0, bf1;
#pragma unroll
            for (int jj = 0; jj < 4; ++jj) {
                bf0.u[jj] = pack_bf16(xlv0 * bf2f(xa[2 * jj]), xlv0 * bf2f(xa[2 * jj + 1]));
                bf1.u[jj] = pack_bf16(xlv1 * bf2f(xb[2 * jj]), xlv1 * bf2f(xb[2 * jj + 1]));
            }

            // A fragments: W[o = tile + row_lane, c = cbase + kgrp*8 + j]
            short8 af[4];
#pragma unroll
            for (int ot = 0; ot < 4; ++ot) {
                if (USE_WS) {
                    af[ot] = *(const short8*)(wrow[ot] + cbase);
                } else {
                    float4 wv0 = *(const float4*)(wrowf[ot] + cbase);
                    float4 wv1 = *(const float4*)(wrowf[ot] + cbase + 4);
                    union { short8 s; uint32_t u[4]; } cc;
                    cc.u[0] = pack_bf16(wv0.x, wv0.y);
                    cc.u[1] = pack_bf16(wv0.z, wv0.w);
                    cc.u[2] = pack_bf16(wv1.x, wv1.y);
                    cc.u[3] = pack_bf16(wv1.z, wv1.w);
                    af[ot] = cc.s;
                }
            }

#pragma unroll
            for (int ot = 0; ot < 4; ++ot) {
                acc[ot][0] = __builtin_amdgcn_mfma_f32_16x16x32_bf16(af[ot], bf0.s, acc[ot][0], 0, 0, 0);
                acc[ot][1] = __builtin_amdgcn_mfma_f32_16x16x32_bf16(af[ot], bf1.s, acc[ot][1], 0, 0, 0);
            }
        }
    }

    // ---------- epilogue: bias + store ----------
    // C/D layout (16x16x32): col = lane&15, row = (lane>>4)*4 + reg
    const int kcol0 = wave_k * 32 + row_lane;
    float* outb = out + (size_t)b * (OUT_SZ * K_SZ);
#pragma unroll
    for (int ot = 0; ot < 4; ++ot) {
        const int o0 = obase + ot * 16 + kgrp * 4;
#pragma unroll
        for (int r = 0; r < 4; ++r) {
            const float bv = bias[o0 + r];
            outb[(o0 + r) * K_SZ + kcol0]      = acc[ot][0][r] + bv;
            outb[(o0 + r) * K_SZ + kcol0 + 16] = acc[ot][1][r] + bv;
        }
    }
}

extern "C" void kernel_launch(void* const* d_in, const int* in_sizes, int n_in,
                              void* d_out, int out_size, void* d_ws, size_t ws_size,
                              hipStream_t stream) {
    const float* x0   = (const float*)d_in[0];
    const float* xl   = (const float*)d_in[1];
    // d_in[2] is the scalar k (=128) — fixed by the problem shape
    const float* W    = (const float*)d_in[3];
    const float* bias = (const float*)d_in[4];
    float* out = (float*)d_out;

    const size_t w_bytes = (size_t)OUT_SZ * C_SZ * sizeof(short);
    const bool use_ws = ws_size >= w_bytes;
    short* Wb = (short*)d_ws;

    if (use_ws) {
        const int n = OUT_SZ * C_SZ;
        convert_W<<<dim3(n / (256 * 4)), dim3(256), 0, stream>>>(W, Wb, n);
        cin_main<true><<<dim3(2, B_SZ), dim3(512), 0, stream>>>(x0, xl, W, Wb, bias, out);
    } else {
        cin_main<false><<<dim3(2, B_SZ), dim3(512), 0, stream>>>(x0, xl, W, Wb, bias, out);
    }
}

// Round 2
// 88.119 us; speedup vs baseline: 2.7520x; 2.7520x over previous
//
#include <hip/hip_runtime.h>
#include <hip/hip_bf16.h>
#include <stdint.h>

// out[b,o,k] = sum_{h,m} W[o, h*64+m] * xl[b,h,k] * x0[b,m,k] + bias[o]
// B=256, M=H=64, K=128, OUT=256, C=4096.
// v2: W pre-tiled (bf16, MFMA-subtile order) in d_ws; double-buffered LDS
// staging via global_load_lds(16B); x0 fragments hoisted to registers
// (h-invariant); xl f32 in LDS; 2-phase pipeline, 1 barrier per c-chunk.

typedef __attribute__((ext_vector_type(8))) short short8;
typedef __attribute__((ext_vector_type(4))) float f32x4;

#define B_SZ   256
#define K_SZ   128
#define OUT_SZ 256
#define C_SZ   4096
#define NCHUNK 64          // one chunk = one h (64 c-values = 2 cb blocks of 32)

__device__ __forceinline__ uint32_t pack_bf16(float a, float b) {
    __hip_bfloat162 h2 = __float22bfloat162_rn(make_float2(a, b));
    union { __hip_bfloat162 h; uint32_t u; } v;
    v.h = h2;
    return v.u;
}

__device__ __forceinline__ void load_lds_16(const void* g, void* l) {
    __builtin_amdgcn_global_load_lds(
        (const __attribute__((address_space(1))) unsigned int*)g,
        (__attribute__((address_space(3))) unsigned int*)l,
        16, 0, 0);
}

// ---- W f32 -> bf16 tiled layout in d_ws ----
// tiled short index = ((g_ot*128 + cb)*64 + lane)*8 + j
//   g_ot = o/16 (0..15), cb = c/32 (0..127), lane = (c%32/8)*16 + o%16
//   element (o = g_ot*16 + (lane&15), c = cb*32 + (lane>>4)*8 + j)
// Each 1KB subtile is exactly one wave's A-fragment load (lane-linear).
__global__ void convert_W_tiled(const float* __restrict__ W, short* __restrict__ Wb) {
    int t = blockIdx.x * blockDim.x + threadIdx.x;   // 0..131071
    int lane = t & 63;
    int cb   = (t >> 6) & 127;
    int got  = t >> 13;
    int o = got * 16 + (lane & 15);
    int c = cb * 32 + (lane >> 4) * 8;
    const float* p = W + (size_t)o * C_SZ + c;
    float4 w0 = *(const float4*)p;
    float4 w1 = *(const float4*)(p + 4);
    union { short8 s; uint32_t u[4]; } cc;
    cc.u[0] = pack_bf16(w0.x, w0.y);
    cc.u[1] = pack_bf16(w0.z, w0.w);
    cc.u[2] = pack_bf16(w1.x, w1.y);
    cc.u[3] = pack_bf16(w1.z, w1.w);
    *(short8*)(Wb + (size_t)t * 8) = cc.s;
}

// ---- main kernel ----
// grid (2, 256): blockIdx.x = o-half (128 rows), blockIdx.y = b
// 512 threads = 8 waves: wo = wave>>2 (2: o64 tiles), wk = wave&3 (4: k32 tiles)
// wave frags: 4 o-tiles x 2 n-tiles of 16x16; K-loop chunked by h (64 c each)
template<bool USE_WS>
__global__ __launch_bounds__(512, 4)
void cin_main(const float* __restrict__ x0, const float* __restrict__ xl,
              const float* __restrict__ Wf, const short* __restrict__ Wb,
              const float* __restrict__ bias, float* __restrict__ out) {
    __shared__ float xlf[64 * 128];          // 32 KB, [h][k] f32
    __shared__ short Wlds[2 * 8192];         // 2 x 16 KB chunk buffers

    const int b     = blockIdx.y;
    const int ohalf = blockIdx.x;
    const int tid   = threadIdx.x;
    const int lane  = tid & 63;
    const int wave  = tid >> 6;
    const int wk    = wave & 3;              // k offset *32
    const int wo    = wave >> 2;             // o offset *64
    const int rl    = lane & 15;
    const int kg    = lane >> 4;             // c-subgroup *8

    // ---- stage xl (f32) into LDS: 8192 floats, 16 per thread ----
    {
        const float4* src = (const float4*)(xl + (size_t)b * (64 * K_SZ));
        float4* dst = (float4*)xlf;
#pragma unroll
        for (int i = 0; i < 4; ++i)
            dst[tid * 4 + i] = src[tid * 4 + i];
    }

    // ---- hoist x0 fragments to registers (h-invariant!) ----
    // x0f[mi][nt][j] = x0[b, mi*32 + kg*8 + j, wk*32 + nt*16 + rl]
    float x0f[2][2][8];
    {
        const float* x0b = x0 + (size_t)b * (64 * K_SZ);
        const int col0 = wk * 32 + rl;
#pragma unroll
        for (int mi = 0; mi < 2; ++mi)
#pragma unroll
            for (int j = 0; j < 8; ++j) {
                const float* r = x0b + (mi * 32 + kg * 8 + j) * K_SZ + col0;
                x0f[mi][0][j] = r[0];
                x0f[mi][1][j] = r[16];
            }
    }

    // ---- W staging setup ----
    // chunk h needs cb = 2h, 2h+1 for g_ot = ohalf*8 .. +8.
    // wave w stages subtiles (g_ot_local=w, cbl=0,1): 2 x global_load_lds(16B)
    const short* wsrc = Wb + ((size_t)(ohalf * 8 + wave) * 128) * 512 + lane * 8;
    const float* wfrow = Wf + (size_t)((ohalf * 8 + wave) * 16 + rl) * C_SZ + kg * 8;
    short* wdst0 = Wlds + (wave * 2 + 0) * 512;
    short* wdst1 = Wlds + (wave * 2 + 1) * 512;
    short* wown  = Wlds + (wave * 2) * 512 + lane * 8;   // fallback write spot

    auto stage = [&](int buf, int h) {
        if (USE_WS) {
            const short* s = wsrc + (size_t)h * 1024;    // cb = 2h
            load_lds_16(s,       wdst0 + buf * 8192);
            load_lds_16(s + 512, wdst1 + buf * 8192);
        } else {
#pragma unroll
            for (int cbl = 0; cbl < 2; ++cbl) {
                const float* p = wfrow + (2 * h + cbl) * 32;
                float4 w0 = *(const float4*)p;
                float4 w1 = *(const float4*)(p + 4);
                union { short8 s; uint32_t u[4]; } cc;
                cc.u[0] = pack_bf16(w0.x, w0.y);
                cc.u[1] = pack_bf16(w0.z, w0.w);
                cc.u[2] = pack_bf16(w1.x, w1.y);
                cc.u[3] = pack_bf16(w1.z, w1.w);
                *(short8*)(wown + buf * 8192 + cbl * 512) = cc.s;
            }
        }
    };

    f32x4 acc[4][2];
#pragma unroll
    for (int ot = 0; ot < 4; ++ot)
#pragma unroll
        for (int nt = 0; nt < 2; ++nt)
            acc[ot][nt] = (f32x4){0.f, 0.f, 0.f, 0.f};

    // prologue: stage chunk 0 into buffer 0
    stage(0, 0);
    __syncthreads();

    const float* xlrow = xlf + wk * 32 + rl;
    int cur = 0;

    for (int h = 0; h < NCHUNK; ++h) {
        if (h < NCHUNK - 1) stage(cur ^ 1, h + 1);

        const float xlv0 = xlrow[h * K_SZ];
        const float xlv1 = xlrow[h * K_SZ + 16];

#pragma unroll
        for (int mi = 0; mi < 2; ++mi) {
            // A-frag base: subtile s = (wo*4+ot)*2 + mi -> shorts (wo*8+mi)*512 + ot*1024
            const short* wbase = Wlds + cur * 8192 + (wo * 8 + mi) * 512 + lane * 8;

            // B-frags: fmap[c = h*64 + mi*32 + kg*8 + j, n] = xl[h,n] * x0[m,n]
            union { short8 s; uint32_t u[4]; } bf0, bf1;
#pragma unroll
            for (int jj = 0; jj < 4; ++jj) {
                bf0.u[jj] = pack_bf16(xlv0 * x0f[mi][0][2 * jj], xlv0 * x0f[mi][0][2 * jj + 1]);
                bf1.u[jj] = pack_bf16(xlv1 * x0f[mi][1][2 * jj], xlv1 * x0f[mi][1][2 * jj + 1]);
            }

#pragma unroll
            for (int ot = 0; ot < 4; ++ot) {
                const short8 af = *(const short8*)(wbase + ot * 1024);
                acc[ot][0] = __builtin_amdgcn_mfma_f32_16x16x32_bf16(af, bf0.s, acc[ot][0], 0, 0, 0);
                acc[ot][1] = __builtin_amdgcn_mfma_f32_16x16x32_bf16(af, bf1.s, acc[ot][1], 0, 0, 0);
            }
        }
        __syncthreads();
        cur ^= 1;
    }

    // ---- epilogue: bias + store ----
    // C/D layout (16x16x32): col = lane&15, row = (lane>>4)*4 + reg
    const int obase = ohalf * 128 + wo * 64;
    const int kcol0 = wk * 32 + rl;
    float* outb = out + (size_t)b * (OUT_SZ * K_SZ);
#pragma unroll
    for (int ot = 0; ot < 4; ++ot) {
        const int o0 = obase + ot * 16 + kg * 4;
#pragma unroll
        for (int r = 0; r < 4; ++r) {
            const float bv = bias[o0 + r];
            outb[(o0 + r) * K_SZ + kcol0]      = acc[ot][0][r] + bv;
            outb[(o0 + r) * K_SZ + kcol0 + 16] = acc[ot][1][r] + bv;
        }
    }
}

extern "C" void kernel_launch(void* const* d_in, const int* in_sizes, int n_in,
                              void* d_out, int out_size, void* d_ws, size_t ws_size,
                              hipStream_t stream) {
    const float* x0   = (const float*)d_in[0];
    const float* xl   = (const float*)d_in[1];
    // d_in[2] is the scalar k (=128) — fixed by the problem shape
    const float* W    = (const float*)d_in[3];
    const float* bias = (const float*)d_in[4];
    float* out = (float*)d_out;

    const size_t w_bytes = (size_t)OUT_SZ * C_SZ * sizeof(short);
    short* Wb = (short*)d_ws;

    if (ws_size >= w_bytes) {
        convert_W_tiled<<<dim3(512), dim3(256), 0, stream>>>(W, Wb);
        cin_main<true><<<dim3(2, B_SZ), dim3(512), 0, stream>>>(x0, xl, W, Wb, bias, out);
    } else {
        cin_main<false><<<dim3(2, B_SZ), dim3(512), 0, stream>>>(x0, xl, W, Wb, bias, out);
    }
}

// Round 3
// 77.572 us; speedup vs baseline: 3.1261x; 1.1360x over previous
//
#include <hip/hip_runtime.h>
#include <hip/hip_bf16.h>
#include <stdint.h>

// out[b,o,k] = sum_{h,m} W[o, h*64+m] * xl[b,h,k] * x0[b,m,k] + bias[o]
// B=256, M=H=64, K=128, OUT=256, C=4096.
// v3: algebraic refactor  out = sum_h xl[h,n] * (W_h @ x0)  — the MFMA B-operand
// (x0, bf16) is h-invariant and lives in registers; per-h work is 4 ds_read_b128
// (W A-frags, pre-tiled in d_ws) + 16 MFMA + 32 v_fma. Waves: 4(o) x 2(k) ->
// W re-read duplication halved vs v2. Double-buffered W staging, 1 barrier/h.

typedef __attribute__((ext_vector_type(8))) short short8;
typedef __attribute__((ext_vector_type(4))) float f32x4;

#define B_SZ   256
#define K_SZ   128
#define OUT_SZ 256
#define C_SZ   4096
#define NCHUNK 64

__device__ __forceinline__ uint32_t pack_bf16(float a, float b) {
    __hip_bfloat162 h2 = __float22bfloat162_rn(make_float2(a, b));
    union { __hip_bfloat162 h; uint32_t u; } v;
    v.h = h2;
    return v.u;
}

__device__ __forceinline__ void load_lds_16(const void* g, void* l) {
    __builtin_amdgcn_global_load_lds(
        (const __attribute__((address_space(1))) unsigned int*)g,
        (__attribute__((address_space(3))) unsigned int*)l,
        16, 0, 0);
}

// ---- W f32 -> bf16 tiled layout in d_ws ----
// tiled short index = ((g_ot*128 + cb)*64 + lane)*8 + j
//   g_ot = o/16, cb = c/32, lane = (c%32/8)*16 + o%16
//   element (o = g_ot*16 + (lane&15), c = cb*32 + (lane>>4)*8 + j)
__global__ void convert_W_tiled(const float* __restrict__ W, short* __restrict__ Wb) {
    int t = blockIdx.x * blockDim.x + threadIdx.x;   // 0..131071
    int lane = t & 63;
    int cb   = (t >> 6) & 127;
    int got  = t >> 13;
    int o = got * 16 + (lane & 15);
    int c = cb * 32 + (lane >> 4) * 8;
    const float* p = W + (size_t)o * C_SZ + c;
    float4 w0 = *(const float4*)p;
    float4 w1 = *(const float4*)(p + 4);
    union { short8 s; uint32_t u[4]; } cc;
    cc.u[0] = pack_bf16(w0.x, w0.y);
    cc.u[1] = pack_bf16(w0.z, w0.w);
    cc.u[2] = pack_bf16(w1.x, w1.y);
    cc.u[3] = pack_bf16(w1.z, w1.w);
    *(short8*)(Wb + (size_t)t * 8) = cc.s;
}

// ---- main kernel ----
// grid (2, 256): blockIdx.x = o-half (128 rows), blockIdx.y = b
// 512 threads = 8 waves: wo = wave>>1 (4: o32 tiles), wk = wave&1 (2: k64 tiles)
// per wave: 2 o-frags x 4 n-frags of 16x16; c-loop chunked by h (64 c each)
template<bool USE_WS>
__global__ __launch_bounds__(512, 4)
void cin_main(const float* __restrict__ x0, const float* __restrict__ xl,
              const float* __restrict__ Wf, const short* __restrict__ Wb,
              const float* __restrict__ bias, float* __restrict__ out) {
    __shared__ float xlf[64 * 128];          // 32 KB, [h][k] f32
    __shared__ short Wlds[2 * 8192];         // 2 x 16 KB chunk buffers

    const int b     = blockIdx.y;
    const int ohalf = blockIdx.x;
    const int tid   = threadIdx.x;
    const int lane  = tid & 63;
    const int wave  = tid >> 6;
    const int wo    = wave >> 1;             // 0..3, o offset *32
    const int wk    = wave & 1;              // 0..1, k offset *64
    const int rl    = lane & 15;
    const int kg    = lane >> 4;             // c-subgroup *8

    // ---- stage xl (f32) into LDS ----
    {
        const float4* src = (const float4*)(xl + (size_t)b * (64 * K_SZ));
        float4* dst = (float4*)xlf;
#pragma unroll
        for (int i = 0; i < 4; ++i)
            dst[tid * 4 + i] = src[tid * 4 + i];
    }

    // ---- x0 B-fragments, bf16-packed, h-invariant: 32 VGPRs ----
    // x0p[ks][nt] holds B[k = kg*8+j][n = wk*64 + nt*16 + rl] of x0 rows ks*32..+32
    union { short8 s; uint32_t u[4]; } x0p[2][4];
    {
        const float* x0b = x0 + (size_t)b * (64 * K_SZ);
        const int col0 = wk * 64 + rl;
#pragma unroll
        for (int ks = 0; ks < 2; ++ks)
#pragma unroll
            for (int nt = 0; nt < 4; ++nt)
#pragma unroll
                for (int j = 0; j < 4; ++j) {
                    const int r0 = ks * 32 + kg * 8 + 2 * j;
                    const int cc = col0 + nt * 16;
                    x0p[ks][nt].u[j] = pack_bf16(x0b[r0 * K_SZ + cc],
                                                 x0b[(r0 + 1) * K_SZ + cc]);
                }
    }

    // ---- W staging setup (identical layout to v2) ----
    const short* wsrc = Wb + ((size_t)(ohalf * 8 + wave) * 128) * 512 + lane * 8;
    const float* wfrow = Wf + (size_t)((ohalf * 8 + wave) * 16 + rl) * C_SZ + kg * 8;
    short* wdst0 = Wlds + (wave * 2 + 0) * 512;
    short* wdst1 = Wlds + (wave * 2 + 1) * 512;
    short* wown  = Wlds + (wave * 2) * 512 + lane * 8;

    auto stage = [&](int buf, int h) {
        if (USE_WS) {
            const short* s = wsrc + (size_t)h * 1024;
            load_lds_16(s,       wdst0 + buf * 8192);
            load_lds_16(s + 512, wdst1 + buf * 8192);
        } else {
#pragma unroll
            for (int cbl = 0; cbl < 2; ++cbl) {
                const float* p = wfrow + (2 * h + cbl) * 32;
                float4 w0 = *(const float4*)p;
                float4 w1 = *(const float4*)(p + 4);
                union { short8 s; uint32_t u[4]; } cc;
                cc.u[0] = pack_bf16(w0.x, w0.y);
                cc.u[1] = pack_bf16(w0.z, w0.w);
                cc.u[2] = pack_bf16(w1.x, w1.y);
                cc.u[3] = pack_bf16(w1.z, w1.w);
                *(short8*)(wown + buf * 8192 + cbl * 512) = cc.s;
            }
        }
    };

    f32x4 acc[2][4];
#pragma unroll
    for (int ot = 0; ot < 2; ++ot)
#pragma unroll
        for (int nt = 0; nt < 4; ++nt)
            acc[ot][nt] = (f32x4){0.f, 0.f, 0.f, 0.f};
    const f32x4 kz = (f32x4){0.f, 0.f, 0.f, 0.f};

    stage(0, 0);
    __syncthreads();

    const float* xlrow = xlf + wk * 64 + rl;
    int cur = 0;

    for (int h = 0; h < NCHUNK; ++h) {
        if (h < NCHUNK - 1) stage(cur ^ 1, h + 1);

        float xlv[4];
#pragma unroll
        for (int nt = 0; nt < 4; ++nt)
            xlv[nt] = xlrow[h * K_SZ + nt * 16];

#pragma unroll
        for (int ot = 0; ot < 2; ++ot) {
            const short* wb = Wlds + cur * 8192 + ((wo * 2 + ot) * 2) * 512 + lane * 8;
            const short8 af0 = *(const short8*)(wb);
            const short8 af1 = *(const short8*)(wb + 512);
#pragma unroll
            for (int nt = 0; nt < 4; ++nt) {
                f32x4 g = __builtin_amdgcn_mfma_f32_16x16x32_bf16(af0, x0p[0][nt].s, kz, 0, 0, 0);
                g = __builtin_amdgcn_mfma_f32_16x16x32_bf16(af1, x0p[1][nt].s, g, 0, 0, 0);
#pragma unroll
                for (int r = 0; r < 4; ++r)
                    acc[ot][nt][r] += xlv[nt] * g[r];
            }
        }
        __syncthreads();
        cur ^= 1;
    }

    // ---- epilogue: bias + store ----
    // C/D layout (16x16x32): col = lane&15, row = (lane>>4)*4 + reg
    float* outb = out + (size_t)b * (OUT_SZ * K_SZ);
#pragma unroll
    for (int ot = 0; ot < 2; ++ot) {
        const int o0 = ohalf * 128 + wo * 32 + ot * 16 + kg * 4;
#pragma unroll
        for (int r = 0; r < 4; ++r) {
            const float bv = bias[o0 + r];
#pragma unroll
            for (int nt = 0; nt < 4; ++nt)
                outb[(o0 + r) * K_SZ + wk * 64 + nt * 16 + rl] = acc[ot][nt][r] + bv;
        }
    }
}

extern "C" void kernel_launch(void* const* d_in, const int* in_sizes, int n_in,
                              void* d_out, int out_size, void* d_ws, size_t ws_size,
                              hipStream_t stream) {
    const float* x0   = (const float*)d_in[0];
    const float* xl   = (const float*)d_in[1];
    // d_in[2] is the scalar k (=128) — fixed by the problem shape
    const float* W    = (const float*)d_in[3];
    const float* bias = (const float*)d_in[4];
    float* out = (float*)d_out;

    const size_t w_bytes = (size_t)OUT_SZ * C_SZ * sizeof(short);
    short* Wb = (short*)d_ws;

    if (ws_size >= w_bytes) {
        convert_W_tiled<<<dim3(512), dim3(256), 0, stream>>>(W, Wb);
        cin_main<true><<<dim3(2, B_SZ), dim3(512), 0, stream>>>(x0, xl, W, Wb, bias, out);
    } else {
        cin_main<false><<<dim3(2, B_SZ), dim3(512), 0, stream>>>(x0, xl, W, Wb, bias, out);
    }
}